// Round 2
// baseline (1337.501 us; speedup 1.0000x reference)
//
#include <hip/hip_runtime.h>
#include <stdint.h>

#define B_SZ 32
#define C_SZ 64
#define N_SZ 65536
#define K_SZ 8192
#define NB   256      // sort chunks (blocks) per batch
#define CHUNK 256     // elements per chunk (1 per thread)

__device__ __forceinline__ uint32_t rotl32(uint32_t v, int r) {
  return (v << r) | (v >> (32 - r));
}

// JAX Threefry-2x32, 20 rounds.
__device__ __forceinline__ void threefry2x32(uint32_t k0, uint32_t k1,
                                             uint32_t x0, uint32_t x1,
                                             uint32_t& o0, uint32_t& o1) {
  const uint32_t ks2 = k0 ^ k1 ^ 0x1BD11BDAu;
  x0 += k0; x1 += k1;
#define TF_R(r) { x0 += x1; x1 = rotl32(x1, (r)); x1 ^= x0; }
  TF_R(13) TF_R(15) TF_R(26) TF_R(6)   x0 += k1;  x1 += ks2 + 1u;
  TF_R(17) TF_R(29) TF_R(16) TF_R(24)  x0 += ks2; x1 += k0  + 2u;
  TF_R(13) TF_R(15) TF_R(26) TF_R(6)   x0 += k0;  x1 += k1  + 3u;
  TF_R(17) TF_R(29) TF_R(16) TF_R(24)  x0 += k1;  x1 += ks2 + 4u;
  TF_R(13) TF_R(15) TF_R(26) TF_R(6)   x0 += ks2; x1 += k0  + 5u;
#undef TF_R
  o0 = x0; o1 = x1;
}

// subkey for batch b, shuffle round `round` (0 or 1), partitionable semantics.
__device__ __forceinline__ void subkey_for_round(int b, int round,
                                                 uint32_t& sk0, uint32_t& sk1) {
  uint32_t c0, c1;
  threefry2x32(0u, 1u, 0u, (uint32_t)b, c0, c1);
  for (int r = 0; r < round; ++r) {
    uint32_t n0, n1;
    threefry2x32(c0, c1, 0u, 0u, n0, n1);
    c0 = n0; c1 = n1;
  }
  threefry2x32(c0, c1, 0u, 1u, sk0, sk1);
}

// ---- round-1 keygen + fused pass-1 histogram ----
__global__ __launch_bounds__(256) void gen1_hist(uint64_t* __restrict__ ping,
                                                 uint32_t* __restrict__ ghist) {
  __shared__ uint32_t h[256];
  const int t = threadIdx.x, blk = blockIdx.x, b = blockIdx.y;
  h[t] = 0; __syncthreads();
  const int i = blk * CHUNK + t;
  uint32_t sk0, sk1, o0, o1;
  subkey_for_round(b, 0, sk0, sk1);
  threefry2x32(sk0, sk1, 0u, (uint32_t)i, o0, o1);
  const uint32_t bits = o0 ^ o1;
  ping[(size_t)b * N_SZ + i] = ((uint64_t)bits << 16) | (uint64_t)i;
  atomicAdd(&h[bits & 0xFFu], 1u);
  __syncthreads();
  ghist[((size_t)b * NB + blk) * 256 + t] = h[t];
}

// ---- round-2 keygen (value = round-1 sorted value) + fused histogram ----
__global__ __launch_bounds__(256) void gen2_hist(const uint64_t* __restrict__ sorted1,
                                                 uint64_t* __restrict__ out,
                                                 uint32_t* __restrict__ ghist) {
  __shared__ uint32_t h[256];
  const int t = threadIdx.x, blk = blockIdx.x, b = blockIdx.y;
  h[t] = 0; __syncthreads();
  const int i = blk * CHUNK + t;
  uint32_t sk0, sk1, o0, o1;
  subkey_for_round(b, 1, sk0, sk1);
  threefry2x32(sk0, sk1, 0u, (uint32_t)i, o0, o1);
  const uint32_t bits = o0 ^ o1;
  const uint64_t val = sorted1[(size_t)b * N_SZ + i] & 0xFFFFull;
  out[(size_t)b * N_SZ + i] = ((uint64_t)bits << 16) | val;
  atomicAdd(&h[bits & 0xFFu], 1u);
  __syncthreads();
  ghist[((size_t)b * NB + blk) * 256 + t] = h[t];
}

// ---- per-chunk histogram for a later pass ----
template <int SHIFT>
__global__ __launch_bounds__(256) void hist_kernel(const uint64_t* __restrict__ src,
                                                   uint32_t* __restrict__ ghist) {
  __shared__ uint32_t h[256];
  const int t = threadIdx.x, blk = blockIdx.x, b = blockIdx.y;
  h[t] = 0; __syncthreads();
  const uint64_t v = src[(size_t)b * N_SZ + blk * CHUNK + t];
  atomicAdd(&h[(uint32_t)(v >> SHIFT) & 0xFFu], 1u);
  __syncthreads();
  ghist[((size_t)b * NB + blk) * 256 + t] = h[t];
}

// ---- per-batch prefix: gbase[b][blk][d] = sum over blk'<blk; dbase[b][d] = digit base ----
__global__ __launch_bounds__(256) void prefix_kernel(const uint32_t* __restrict__ ghist,
                                                     uint32_t* __restrict__ gbase,
                                                     uint32_t* __restrict__ dbase) {
  __shared__ uint32_t totals[256];
  const int b = blockIdx.x, d = threadIdx.x;
  const uint32_t* __restrict__ h = ghist + (size_t)b * NB * 256;
  uint32_t* __restrict__ g = gbase + (size_t)b * NB * 256;
  uint32_t run = 0;
#pragma unroll 8
  for (int blk = 0; blk < NB; ++blk) {
    const uint32_t x = h[blk * 256 + d];
    g[blk * 256 + d] = run;
    run += x;
  }
  totals[d] = run;
  __syncthreads();
  if (d == 0) {
    uint32_t r = 0;
#pragma unroll
    for (int i = 0; i < 256; ++i) { const uint32_t x = totals[i]; totals[i] = r; r += x; }
  }
  __syncthreads();
  dbase[b * 256 + d] = totals[d];
}

// ---- stable scatter: pos = dbase + gbase + (#earlier-threads-in-chunk w/ same digit) ----
template <int SHIFT, bool EXTRACT>
__global__ __launch_bounds__(256) void scatter_kernel(const uint64_t* __restrict__ src,
                                                      uint64_t* __restrict__ dst,
                                                      const uint32_t* __restrict__ gbase,
                                                      const uint32_t* __restrict__ dbase,
                                                      uint32_t* __restrict__ idx) {
  __shared__ uint8_t cnt[256 * 260];  // [thread][digit], stride 260 to spread banks
  const int t = threadIdx.x, blk = blockIdx.x, b = blockIdx.y;

  uint32_t* __restrict__ c32 = (uint32_t*)cnt;
#pragma unroll
  for (int k = 0; k < (256 * 260 / 4) / 256; ++k)  // 65 iterations, exact
    c32[k * 256 + t] = 0;
  __syncthreads();

  const uint64_t v = src[(size_t)b * N_SZ + blk * CHUNK + t];
  const uint32_t dg = (uint32_t)(v >> SHIFT) & 0xFFu;
  cnt[t * 260 + dg] = 1;
  __syncthreads();

  {  // exclusive prefix over threads, one digit column per thread
    const int d = ((t & 63) << 2) | (t >> 6);  // bank-friendly digit assignment
    uint32_t run = 0;
#pragma unroll 8
    for (int tt = 0; tt < 256; ++tt) {
      const uint8_t x = cnt[tt * 260 + d];
      cnt[tt * 260 + d] = (uint8_t)run;
      run += x;
    }
  }
  __syncthreads();

  const uint32_t pos = dbase[b * 256 + dg] +
                       gbase[((size_t)b * NB + blk) * 256 + dg] +
                       (uint32_t)cnt[t * 260 + dg];
  dst[(size_t)b * N_SZ + pos] = v;
  if (EXTRACT) {
    if (pos < K_SZ) idx[(size_t)b * K_SZ + pos] = (uint32_t)(v & 0xFFFFull);
  }
}

__global__ __launch_bounds__(256) void gather_kernel(const float* __restrict__ x,
                                                     const uint32_t* __restrict__ idx,
                                                     float* __restrict__ y) {
  const int k = blockIdx.x * 256 + threadIdx.x;
  const int c = blockIdx.y;
  const int b = blockIdx.z;
  const uint32_t j = idx[(size_t)b * K_SZ + k];
  y[((size_t)(b * C_SZ + c)) * K_SZ + k] = x[((size_t)(b * C_SZ + c)) * N_SZ + j];
}

extern "C" void kernel_launch(void* const* d_in, const int* in_sizes, int n_in,
                              void* d_out, int out_size, void* d_ws, size_t ws_size,
                              hipStream_t stream) {
  (void)in_sizes; (void)n_in; (void)out_size; (void)ws_size;
  const float* x = (const float*)d_in[0];
  float* y = (float*)d_out;

  // Scratch inside d_out (64 MB): ping 16 | pong 16 | ghist 8 | gbase 8 | dbase 32KB.
  // idx (1 MB) in d_ws — gather reads idx while overwriting all of d_out.
  char* base = (char*)d_out;
  uint64_t* ping = (uint64_t*)base;
  uint64_t* pong = (uint64_t*)(base + (16u << 20));
  uint32_t* ghist = (uint32_t*)(base + (32u << 20));
  uint32_t* gbase = (uint32_t*)(base + (40u << 20));
  uint32_t* dbase = (uint32_t*)(base + (48u << 20));
  uint32_t* idx = (uint32_t*)d_ws;

  const dim3 blk(256);
  const dim3 gsort(NB, B_SZ);
  const dim3 gpre(B_SZ);

  // ---- round 1: sort (key1, i) ----
  gen1_hist<<<gsort, blk, 0, stream>>>(ping, ghist);
  prefix_kernel<<<gpre, blk, 0, stream>>>(ghist, gbase, dbase);
  scatter_kernel<16, false><<<gsort, blk, 0, stream>>>(ping, pong, gbase, dbase, nullptr);
  hist_kernel<24><<<gsort, blk, 0, stream>>>(pong, ghist);
  prefix_kernel<<<gpre, blk, 0, stream>>>(ghist, gbase, dbase);
  scatter_kernel<24, false><<<gsort, blk, 0, stream>>>(pong, ping, gbase, dbase, nullptr);
  hist_kernel<32><<<gsort, blk, 0, stream>>>(ping, ghist);
  prefix_kernel<<<gpre, blk, 0, stream>>>(ghist, gbase, dbase);
  scatter_kernel<32, false><<<gsort, blk, 0, stream>>>(ping, pong, gbase, dbase, nullptr);
  hist_kernel<40><<<gsort, blk, 0, stream>>>(pong, ghist);
  prefix_kernel<<<gpre, blk, 0, stream>>>(ghist, gbase, dbase);
  scatter_kernel<40, false><<<gsort, blk, 0, stream>>>(pong, ping, gbase, dbase, nullptr);
  // ping = round-1 sorted

  // ---- round 2: rekey, sort (key2, sorted1-val) ----
  gen2_hist<<<gsort, blk, 0, stream>>>(ping, pong, ghist);
  prefix_kernel<<<gpre, blk, 0, stream>>>(ghist, gbase, dbase);
  scatter_kernel<16, false><<<gsort, blk, 0, stream>>>(pong, ping, gbase, dbase, nullptr);
  hist_kernel<24><<<gsort, blk, 0, stream>>>(ping, ghist);
  prefix_kernel<<<gpre, blk, 0, stream>>>(ghist, gbase, dbase);
  scatter_kernel<24, false><<<gsort, blk, 0, stream>>>(ping, pong, gbase, dbase, nullptr);
  hist_kernel<32><<<gsort, blk, 0, stream>>>(pong, ghist);
  prefix_kernel<<<gpre, blk, 0, stream>>>(ghist, gbase, dbase);
  scatter_kernel<32, false><<<gsort, blk, 0, stream>>>(pong, ping, gbase, dbase, nullptr);
  hist_kernel<40><<<gsort, blk, 0, stream>>>(ping, ghist);
  prefix_kernel<<<gpre, blk, 0, stream>>>(ghist, gbase, dbase);
  scatter_kernel<40, true><<<gsort, blk, 0, stream>>>(ping, pong, gbase, dbase, idx);

  // ---- gather ----
  gather_kernel<<<dim3(K_SZ / 256, C_SZ, B_SZ), blk, 0, stream>>>(x, idx, y);
}

// Round 3
// 409.581 us; speedup vs baseline: 3.2655x; 3.2655x over previous
//
#include <hip/hip_runtime.h>
#include <stdint.h>

#define B_SZ 32
#define C_SZ 64
#define N_SZ 65536
#define K_SZ 8192
#define BUCKET_CAP 512

__device__ __forceinline__ uint32_t rotl32(uint32_t v, int r) {
  return (v << r) | (v >> (32 - r));
}

// JAX Threefry-2x32, 20 rounds.
__device__ __forceinline__ void threefry2x32(uint32_t k0, uint32_t k1,
                                             uint32_t x0, uint32_t x1,
                                             uint32_t& o0, uint32_t& o1) {
  const uint32_t ks2 = k0 ^ k1 ^ 0x1BD11BDAu;
  x0 += k0; x1 += k1;
#define TF_R(r) { x0 += x1; x1 = rotl32(x1, (r)); x1 ^= x0; }
  TF_R(13) TF_R(15) TF_R(26) TF_R(6)   x0 += k1;  x1 += ks2 + 1u;
  TF_R(17) TF_R(29) TF_R(16) TF_R(24)  x0 += ks2; x1 += k0  + 2u;
  TF_R(13) TF_R(15) TF_R(26) TF_R(6)   x0 += k0;  x1 += k1  + 3u;
  TF_R(17) TF_R(29) TF_R(16) TF_R(24)  x0 += k1;  x1 += ks2 + 4u;
  TF_R(13) TF_R(15) TF_R(26) TF_R(6)   x0 += ks2; x1 += k0  + 5u;
#undef TF_R
  o0 = x0; o1 = x1;
}

// subkey for batch b, shuffle round `round` (0 or 1), partitionable semantics.
__device__ __forceinline__ void subkey_for_round(int b, int round,
                                                 uint32_t& sk0, uint32_t& sk1) {
  uint32_t c0, c1;
  threefry2x32(0u, 1u, 0u, (uint32_t)b, c0, c1);
  for (int r = 0; r < round; ++r) {
    uint32_t n0, n1;
    threefry2x32(c0, c1, 0u, 0u, n0, n1);
    c0 = n0; c1 = n1;
  }
  threefry2x32(c0, c1, 0u, 1u, sk0, sk1);
}

__global__ __launch_bounds__(256) void zero_hist(uint32_t* __restrict__ hist) {
  hist[blockIdx.x * 256 + threadIdx.x] = 0;
}

// keygen + per-batch top-8-bit histogram. Packs (bits<<16)|i. 4096 elems/block.
template <int ROUND>
__global__ __launch_bounds__(256) void gen_hist(uint64_t* __restrict__ A,
                                                uint32_t* __restrict__ hist) {
  __shared__ uint32_t h[256];
  const int t = threadIdx.x, blk = blockIdx.x, b = blockIdx.y;
  h[t] = 0; __syncthreads();
  uint32_t sk0, sk1;
  subkey_for_round(b, ROUND, sk0, sk1);
  uint64_t* __restrict__ dst = A + (size_t)b * N_SZ;
  const int base = blk * 4096;
#pragma unroll
  for (int e = 0; e < 16; ++e) {
    const int i = base + e * 256 + t;
    uint32_t o0, o1;
    threefry2x32(sk0, sk1, 0u, (uint32_t)i, o0, o1);
    const uint32_t bits = o0 ^ o1;
    dst[i] = ((uint64_t)bits << 16) | (uint64_t)i;
    atomicAdd(&h[bits >> 24], 1u);
  }
  __syncthreads();
  if (h[t]) atomicAdd(&hist[b * 256 + t], h[t]);
}

// per-batch exclusive scan of 256 bucket counts; writes base (257, sentinel N)
// and atomic cursors; re-zeroes hist for the next accumulation / next replay.
__global__ __launch_bounds__(256) void prefix_kernel(uint32_t* __restrict__ hist,
                                                     uint32_t* __restrict__ baseArr,
                                                     uint32_t* __restrict__ cur) {
  __shared__ uint32_t sc[256];
  const int b = blockIdx.x, d = threadIdx.x;
  const uint32_t h = hist[b * 256 + d];
  hist[b * 256 + d] = 0;
  sc[d] = h;
  __syncthreads();
  for (int off = 1; off < 256; off <<= 1) {
    const uint32_t y = (d >= off) ? sc[d - off] : 0u;
    __syncthreads();
    sc[d] += y;
    __syncthreads();
  }
  const uint32_t excl = (d > 0) ? sc[d - 1] : 0u;
  baseArr[b * 257 + d] = excl;
  cur[b * 256 + d] = excl;
  if (d == 255) baseArr[b * 257 + 256] = sc[255];
}

// bucket scatter (order within bucket irrelevant: bitonic restores total order).
__global__ __launch_bounds__(256) void scatter1(const uint64_t* __restrict__ A,
                                                uint64_t* __restrict__ BV,
                                                uint32_t* __restrict__ cur) {
  __shared__ uint32_t lcnt[256];
  __shared__ uint32_t gb[256];
  const int t = threadIdx.x, blk = blockIdx.x, b = blockIdx.y;
  lcnt[t] = 0; __syncthreads();
  const uint64_t* __restrict__ src = A + (size_t)b * N_SZ + blk * 4096;
  uint64_t v[16]; uint32_t r[16], dg[16];
#pragma unroll
  for (int e = 0; e < 16; ++e) {
    v[e] = src[e * 256 + t];
    dg[e] = (uint32_t)(v[e] >> 40) & 0xFFu;
    r[e] = atomicAdd(&lcnt[dg[e]], 1u);
  }
  __syncthreads();
  if (lcnt[t]) gb[t] = atomicAdd(&cur[b * 256 + t], lcnt[t]);
  __syncthreads();
  uint64_t* __restrict__ dst = BV + (size_t)b * N_SZ;
#pragma unroll
  for (int e = 0; e < 16; ++e)
    dst[gb[dg[e]] + r[e]] = v[e];
}

// round-2 scatter: only buckets whose base < K matter for the first K outputs.
__global__ __launch_bounds__(256) void scatter2(const uint64_t* __restrict__ A,
                                                uint64_t* __restrict__ CV,
                                                uint32_t* __restrict__ cur,
                                                const uint32_t* __restrict__ baseArr) {
  __shared__ uint32_t lcnt[256];
  __shared__ uint32_t gb[256];
  __shared__ uint32_t keep[256];
  const int t = threadIdx.x, blk = blockIdx.x, b = blockIdx.y;
  lcnt[t] = 0;
  keep[t] = (baseArr[b * 257 + t] < K_SZ) ? 1u : 0u;
  __syncthreads();
  const uint64_t* __restrict__ src = A + (size_t)b * N_SZ + blk * 4096;
  uint64_t v[16]; uint32_t r[16], dg[16];
#pragma unroll
  for (int e = 0; e < 16; ++e) {
    v[e] = src[e * 256 + t];
    dg[e] = (uint32_t)(v[e] >> 40) & 0xFFu;
    r[e] = keep[dg[e]] ? atomicAdd(&lcnt[dg[e]], 1u) : 0u;
  }
  __syncthreads();
  if (lcnt[t]) gb[t] = atomicAdd(&cur[b * 256 + t], lcnt[t]);
  __syncthreads();
  uint64_t* __restrict__ dst = CV + (size_t)b * N_SZ;
#pragma unroll
  for (int e = 0; e < 16; ++e)
    if (keep[dg[e]]) dst[gb[dg[e]] + r[e]] = v[e];
}

// 512-element bitonic sort in LDS; records are unique -> equals stable sort.
__device__ __forceinline__ void bitonic512(uint64_t* s, int t) {
  for (int k = 2; k <= BUCKET_CAP; k <<= 1) {
    for (int j = k >> 1; j > 0; j >>= 1) {
      __syncthreads();
#pragma unroll
      for (int w = 0; w < 2; ++w) {
        const int i = t + (w << 8);
        const int l = i ^ j;
        if (l > i) {
          const uint64_t a = s[i], c = s[l];
          const bool descend = (i & k) != 0;
          if ((a > c) != descend) { s[i] = c; s[l] = a; }
        }
      }
    }
  }
  __syncthreads();
}

__global__ __launch_bounds__(256) void bucket_sort1(uint64_t* __restrict__ BV,
                                                    const uint32_t* __restrict__ baseArr) {
  __shared__ uint64_t s[BUCKET_CAP];
  const int t = threadIdx.x, u = blockIdx.x, b = blockIdx.y;
  const uint32_t base = baseArr[b * 257 + u];
  uint32_t n = baseArr[b * 257 + u + 1] - base;
  if (n > BUCKET_CAP) n = BUCKET_CAP;  // statistically impossible
  uint64_t* __restrict__ g = BV + (size_t)b * N_SZ + base;
  s[t]       = (t < (int)n)       ? g[t]       : ~0ull;
  s[t + 256] = (t + 256 < (int)n) ? g[t + 256] : ~0ull;
  bitonic512(s, t);
  if (t < (int)n)       g[t]       = s[t];
  if (t + 256 < (int)n) g[t + 256] = s[t + 256];
}

// sort the ~33 head buckets of round 2; emit idx[b][q] = val1 (gathered via s1).
__global__ __launch_bounds__(256) void finalize(const uint64_t* __restrict__ CV,
                                                const uint64_t* __restrict__ S1,
                                                const uint32_t* __restrict__ baseArr,
                                                uint32_t* __restrict__ idx) {
  __shared__ uint64_t s[BUCKET_CAP];
  const int t = threadIdx.x, u = blockIdx.x, b = blockIdx.y;
  const uint32_t base = baseArr[b * 257 + u];
  if (base >= K_SZ) return;
  uint32_t n = baseArr[b * 257 + u + 1] - base;
  if (n > BUCKET_CAP) n = BUCKET_CAP;
  const uint64_t* __restrict__ g = CV + (size_t)b * N_SZ + base;
  s[t]       = (t < (int)n)       ? g[t]       : ~0ull;
  s[t + 256] = (t + 256 < (int)n) ? g[t + 256] : ~0ull;
  bitonic512(s, t);
  const uint64_t* __restrict__ s1 = S1 + (size_t)b * N_SZ;
#pragma unroll
  for (int w = 0; w < 2; ++w) {
    const uint32_t r = (uint32_t)t + (w << 8);
    const uint32_t q = base + r;
    if (r < n && q < K_SZ) {
      const uint32_t p = (uint32_t)(s[r] & 0xFFFFull);
      idx[(size_t)b * K_SZ + q] = (uint32_t)(s1[p] & 0xFFFFull);
    }
  }
}

// gather: 4 channels per thread to amortize idx loads; stores coalesced.
__global__ __launch_bounds__(256) void gather_kernel(const float* __restrict__ x,
                                                     const uint32_t* __restrict__ idx,
                                                     float* __restrict__ y) {
  const int k = blockIdx.x * 256 + threadIdx.x;
  const int c0 = blockIdx.y * 4;
  const int b = blockIdx.z;
  const uint32_t j = idx[(size_t)b * K_SZ + k];
#pragma unroll
  for (int cc = 0; cc < 4; ++cc) {
    const size_t row = (size_t)(b * C_SZ + c0 + cc);
    y[row * K_SZ + k] = x[row * N_SZ + j];
  }
}

extern "C" void kernel_launch(void* const* d_in, const int* in_sizes, int n_in,
                              void* d_out, int out_size, void* d_ws, size_t ws_size,
                              hipStream_t stream) {
  (void)in_sizes; (void)n_in; (void)out_size; (void)ws_size;
  const float* x = (const float*)d_in[0];
  float* y = (float*)d_out;

  // d_out (64 MiB) scratch layout; gather fully overwrites it at the end.
  char* base = (char*)d_out;
  uint64_t* A  = (uint64_t*)base;                     // 16 MiB raw packed (round1 then round2)
  uint64_t* BV = (uint64_t*)(base + (16u << 20));     // 16 MiB bucketed->sorted round1 (s1)
  uint64_t* CV = (uint64_t*)(base + (32u << 20));     // 16 MiB bucketed round2 (head only)
  uint32_t* hist    = (uint32_t*)(base + (48u << 20));            // 32 KiB
  uint32_t* baseArr = (uint32_t*)(base + (48u << 20) + (32u << 10)); // 32x257 u32
  uint32_t* cur     = (uint32_t*)(base + (48u << 20) + (66u << 10)); // 32 KiB
  uint32_t* idx = (uint32_t*)d_ws;                    // 1 MiB

  const dim3 blk(256);
  const dim3 ggen(16, B_SZ);

  zero_hist<<<dim3(B_SZ), blk, 0, stream>>>(hist);
  // round 1
  gen_hist<0><<<ggen, blk, 0, stream>>>(A, hist);
  prefix_kernel<<<dim3(B_SZ), blk, 0, stream>>>(hist, baseArr, cur);
  scatter1<<<ggen, blk, 0, stream>>>(A, BV, cur);
  bucket_sort1<<<dim3(256, B_SZ), blk, 0, stream>>>(BV, baseArr);
  // round 2
  gen_hist<1><<<ggen, blk, 0, stream>>>(A, hist);
  prefix_kernel<<<dim3(B_SZ), blk, 0, stream>>>(hist, baseArr, cur);
  scatter2<<<ggen, blk, 0, stream>>>(A, CV, cur, baseArr);
  finalize<<<dim3(48, B_SZ), blk, 0, stream>>>(CV, BV, baseArr, idx);
  // gather
  gather_kernel<<<dim3(K_SZ / 256, C_SZ / 4, B_SZ), blk, 0, stream>>>(x, idx, y);
}

// Round 4
// 389.879 us; speedup vs baseline: 3.4306x; 1.0505x over previous
//
#include <hip/hip_runtime.h>
#include <stdint.h>

#define B_SZ 32
#define C_SZ 64
#define N_SZ 65536
#define K_SZ 8192
#define BUCKET_CAP 512

__device__ __forceinline__ uint32_t rotl32(uint32_t v, int r) {
  return (v << r) | (v >> (32 - r));
}

// JAX Threefry-2x32, 20 rounds.
__device__ __forceinline__ void threefry2x32(uint32_t k0, uint32_t k1,
                                             uint32_t x0, uint32_t x1,
                                             uint32_t& o0, uint32_t& o1) {
  const uint32_t ks2 = k0 ^ k1 ^ 0x1BD11BDAu;
  x0 += k0; x1 += k1;
#define TF_R(r) { x0 += x1; x1 = rotl32(x1, (r)); x1 ^= x0; }
  TF_R(13) TF_R(15) TF_R(26) TF_R(6)   x0 += k1;  x1 += ks2 + 1u;
  TF_R(17) TF_R(29) TF_R(16) TF_R(24)  x0 += ks2; x1 += k0  + 2u;
  TF_R(13) TF_R(15) TF_R(26) TF_R(6)   x0 += k0;  x1 += k1  + 3u;
  TF_R(17) TF_R(29) TF_R(16) TF_R(24)  x0 += k1;  x1 += ks2 + 4u;
  TF_R(13) TF_R(15) TF_R(26) TF_R(6)   x0 += ks2; x1 += k0  + 5u;
#undef TF_R
  o0 = x0; o1 = x1;
}

__device__ __forceinline__ void subkey_for_round(int b, int round,
                                                 uint32_t& sk0, uint32_t& sk1) {
  uint32_t c0, c1;
  threefry2x32(0u, 1u, 0u, (uint32_t)b, c0, c1);
  for (int r = 0; r < round; ++r) {
    uint32_t n0, n1;
    threefry2x32(c0, c1, 0u, 0u, n0, n1);
    c0 = n0; c1 = n1;
  }
  threefry2x32(c0, c1, 0u, 1u, sk0, sk1);
}

__global__ __launch_bounds__(256) void zero_hist(uint32_t* __restrict__ hist) {
  hist[blockIdx.x * 256 + threadIdx.x] = 0;
}

// keygen + per-batch top-8-bit histogram. Packs (bits<<16)|i. 4096 elems/block.
template <int ROUND>
__global__ __launch_bounds__(256) void gen_hist(uint64_t* __restrict__ A,
                                                uint32_t* __restrict__ hist) {
  __shared__ uint32_t h[256];
  const int t = threadIdx.x, blk = blockIdx.x, b = blockIdx.y;
  h[t] = 0; __syncthreads();
  uint32_t sk0, sk1;
  subkey_for_round(b, ROUND, sk0, sk1);
  uint64_t* __restrict__ dst = A + (size_t)b * N_SZ;
  const int base = blk * 4096;
#pragma unroll
  for (int e = 0; e < 16; ++e) {
    const int i = base + e * 256 + t;
    uint32_t o0, o1;
    threefry2x32(sk0, sk1, 0u, (uint32_t)i, o0, o1);
    const uint32_t bits = o0 ^ o1;
    dst[i] = ((uint64_t)bits << 16) | (uint64_t)i;
    atomicAdd(&h[bits >> 24], 1u);
  }
  __syncthreads();
  if (h[t]) atomicAdd(&hist[b * 256 + t], h[t]);
}

__global__ __launch_bounds__(256) void prefix_kernel(uint32_t* __restrict__ hist,
                                                     uint32_t* __restrict__ baseArr,
                                                     uint32_t* __restrict__ cur) {
  __shared__ uint32_t sc[256];
  const int b = blockIdx.x, d = threadIdx.x;
  const uint32_t h = hist[b * 256 + d];
  hist[b * 256 + d] = 0;
  sc[d] = h;
  __syncthreads();
  for (int off = 1; off < 256; off <<= 1) {
    const uint32_t y = (d >= off) ? sc[d - off] : 0u;
    __syncthreads();
    sc[d] += y;
    __syncthreads();
  }
  const uint32_t excl = (d > 0) ? sc[d - 1] : 0u;
  baseArr[b * 257 + d] = excl;
  cur[b * 256 + d] = excl;
  if (d == 255) baseArr[b * 257 + 256] = sc[255];
}

__global__ __launch_bounds__(256) void scatter1(const uint64_t* __restrict__ A,
                                                uint64_t* __restrict__ BV,
                                                uint32_t* __restrict__ cur) {
  __shared__ uint32_t lcnt[256];
  __shared__ uint32_t gb[256];
  const int t = threadIdx.x, blk = blockIdx.x, b = blockIdx.y;
  lcnt[t] = 0; __syncthreads();
  const uint64_t* __restrict__ src = A + (size_t)b * N_SZ + blk * 4096;
  uint64_t v[16]; uint32_t r[16], dg[16];
#pragma unroll
  for (int e = 0; e < 16; ++e) {
    v[e] = src[e * 256 + t];
    dg[e] = (uint32_t)(v[e] >> 40) & 0xFFu;
    r[e] = atomicAdd(&lcnt[dg[e]], 1u);
  }
  __syncthreads();
  if (lcnt[t]) gb[t] = atomicAdd(&cur[b * 256 + t], lcnt[t]);
  __syncthreads();
  uint64_t* __restrict__ dst = BV + (size_t)b * N_SZ;
#pragma unroll
  for (int e = 0; e < 16; ++e)
    dst[gb[dg[e]] + r[e]] = v[e];
}

__global__ __launch_bounds__(256) void scatter2(const uint64_t* __restrict__ A,
                                                uint64_t* __restrict__ CV,
                                                uint32_t* __restrict__ cur,
                                                const uint32_t* __restrict__ baseArr) {
  __shared__ uint32_t lcnt[256];
  __shared__ uint32_t gb[256];
  __shared__ uint32_t keep[256];
  const int t = threadIdx.x, blk = blockIdx.x, b = blockIdx.y;
  lcnt[t] = 0;
  keep[t] = (baseArr[b * 257 + t] < K_SZ) ? 1u : 0u;
  __syncthreads();
  const uint64_t* __restrict__ src = A + (size_t)b * N_SZ + blk * 4096;
  uint64_t v[16]; uint32_t r[16], dg[16];
#pragma unroll
  for (int e = 0; e < 16; ++e) {
    v[e] = src[e * 256 + t];
    dg[e] = (uint32_t)(v[e] >> 40) & 0xFFu;
    r[e] = keep[dg[e]] ? atomicAdd(&lcnt[dg[e]], 1u) : 0u;
  }
  __syncthreads();
  if (lcnt[t]) gb[t] = atomicAdd(&cur[b * 256 + t], lcnt[t]);
  __syncthreads();
  uint64_t* __restrict__ dst = CV + (size_t)b * N_SZ;
#pragma unroll
  for (int e = 0; e < 16; ++e)
    if (keep[dg[e]]) dst[gb[dg[e]] + r[e]] = v[e];
}

// 512-element bitonic sort in LDS; records unique -> equals stable sort.
__device__ __forceinline__ void bitonic512(uint64_t* s, int t) {
  for (int k = 2; k <= BUCKET_CAP; k <<= 1) {
    for (int j = k >> 1; j > 0; j >>= 1) {
      __syncthreads();
#pragma unroll
      for (int w = 0; w < 2; ++w) {
        const int i = t + (w << 8);
        const int l = i ^ j;
        if (l > i) {
          const uint64_t a = s[i], c = s[l];
          const bool descend = (i & k) != 0;
          if ((a > c) != descend) { s[i] = c; s[l] = a; }
        }
      }
    }
  }
  __syncthreads();
}

__global__ __launch_bounds__(256) void bucket_sort1(uint64_t* __restrict__ BV,
                                                    const uint32_t* __restrict__ baseArr) {
  __shared__ uint64_t s[BUCKET_CAP];
  const int t = threadIdx.x, u = blockIdx.x, b = blockIdx.y;
  const uint32_t base = baseArr[b * 257 + u];
  uint32_t n = baseArr[b * 257 + u + 1] - base;
  if (n > BUCKET_CAP) n = BUCKET_CAP;
  uint64_t* __restrict__ g = BV + (size_t)b * N_SZ + base;
  s[t]       = (t < (int)n)       ? g[t]       : ~0ull;
  s[t + 256] = (t + 256 < (int)n) ? g[t + 256] : ~0ull;
  bitonic512(s, t);
  if (t < (int)n)       g[t]       = s[t];
  if (t + 256 < (int)n) g[t + 256] = s[t + 256];
}

// sort head buckets of round 2; emit packed pair (j<<13)|q into sp (d_ws).
__global__ __launch_bounds__(256) void finalize(const uint64_t* __restrict__ CV,
                                                const uint64_t* __restrict__ S1,
                                                const uint32_t* __restrict__ baseArr,
                                                uint32_t* __restrict__ sp) {
  __shared__ uint64_t s[BUCKET_CAP];
  const int t = threadIdx.x, u = blockIdx.x, b = blockIdx.y;
  const uint32_t base = baseArr[b * 257 + u];
  if (base >= K_SZ) return;
  uint32_t n = baseArr[b * 257 + u + 1] - base;
  if (n > BUCKET_CAP) n = BUCKET_CAP;
  const uint64_t* __restrict__ g = CV + (size_t)b * N_SZ + base;
  s[t]       = (t < (int)n)       ? g[t]       : ~0ull;
  s[t + 256] = (t + 256 < (int)n) ? g[t + 256] : ~0ull;
  bitonic512(s, t);
  const uint64_t* __restrict__ s1 = S1 + (size_t)b * N_SZ;
#pragma unroll
  for (int w = 0; w < 2; ++w) {
    const uint32_t r = (uint32_t)t + (w << 8);
    const uint32_t q = base + r;
    if (r < n && q < K_SZ) {
      const uint32_t p = (uint32_t)(s[r] & 0xFFFFull);      // round-1 rank
      const uint32_t j = (uint32_t)(s1[p] & 0xFFFFull);     // permutation value
      sp[(size_t)b * K_SZ + q] = (j << 13) | q;
    }
  }
}

// in-place per-batch ascending sort of 8192 packed pairs (j major, q minor).
__global__ __launch_bounds__(1024) void sort_pairs(uint32_t* __restrict__ sp) {
  __shared__ uint32_t s[K_SZ];
  const int b = blockIdx.x, t = threadIdx.x;
  uint32_t* __restrict__ g = sp + (size_t)b * K_SZ;
#pragma unroll
  for (int w = 0; w < 8; ++w) s[w * 1024 + t] = g[w * 1024 + t];
  __syncthreads();
  for (int k = 2; k <= K_SZ; k <<= 1) {
    for (int j = k >> 1; j > 0; j >>= 1) {
#pragma unroll 2
      for (int w = 0; w < 4; ++w) {
        const int p = w * 1024 + t;                       // pair id 0..4095
        const int i = ((p & ~(j - 1)) << 1) | (p & (j - 1));
        const int l = i | j;
        const uint32_t a = s[i], c = s[l];
        const bool asc = (i & k) == 0;
        if ((a > c) == asc) { s[i] = c; s[l] = a; }
      }
      __syncthreads();
    }
  }
#pragma unroll
  for (int w = 0; w < 8; ++w) g[w * 1024 + t] = s[w * 1024 + t];
}

// gather in ascending-j order: lanes hit monotone, densely-spaced addresses.
__global__ __launch_bounds__(256) void gather_sorted(const float* __restrict__ x,
                                                     const uint32_t* __restrict__ sp,
                                                     float* __restrict__ y) {
  const int t = threadIdx.x;
  const int seg = blockIdx.x;   // 0..7 (1024 pairs each)
  const int c = blockIdx.y;
  const int b = blockIdx.z;
  const uint32_t* __restrict__ spb = sp + (size_t)b * K_SZ + seg * 1024;
  const float* __restrict__ xr = x + ((size_t)(b * C_SZ + c)) * N_SZ;
  float* __restrict__ yr = y + ((size_t)(b * C_SZ + c)) * K_SZ;
#pragma unroll
  for (int e = 0; e < 4; ++e) {
    const uint32_t p = spb[e * 256 + t];
    yr[p & 8191u] = xr[p >> 13];
  }
}

extern "C" void kernel_launch(void* const* d_in, const int* in_sizes, int n_in,
                              void* d_out, int out_size, void* d_ws, size_t ws_size,
                              hipStream_t stream) {
  (void)in_sizes; (void)n_in; (void)out_size; (void)ws_size;
  const float* x = (const float*)d_in[0];
  float* y = (float*)d_out;

  // d_out (64 MiB) scratch; gather fully overwrites it at the end and reads
  // only x + d_ws. d_ws: 1 MiB packed pairs.
  char* base = (char*)d_out;
  uint64_t* A  = (uint64_t*)base;                     // 16 MiB
  uint64_t* BV = (uint64_t*)(base + (16u << 20));     // 16 MiB (round-1 sorted)
  uint64_t* CV = (uint64_t*)(base + (32u << 20));     // 16 MiB (round-2 head)
  uint32_t* hist    = (uint32_t*)(base + (48u << 20));
  uint32_t* baseArr = (uint32_t*)(base + (48u << 20) + (32u << 10));
  uint32_t* cur     = (uint32_t*)(base + (48u << 20) + (66u << 10));
  uint32_t* sp = (uint32_t*)d_ws;                     // 1 MiB packed (j,q) pairs

  const dim3 blk(256);
  const dim3 ggen(16, B_SZ);

  zero_hist<<<dim3(B_SZ), blk, 0, stream>>>(hist);
  // round 1
  gen_hist<0><<<ggen, blk, 0, stream>>>(A, hist);
  prefix_kernel<<<dim3(B_SZ), blk, 0, stream>>>(hist, baseArr, cur);
  scatter1<<<ggen, blk, 0, stream>>>(A, BV, cur);
  bucket_sort1<<<dim3(256, B_SZ), blk, 0, stream>>>(BV, baseArr);
  // round 2
  gen_hist<1><<<ggen, blk, 0, stream>>>(A, hist);
  prefix_kernel<<<dim3(B_SZ), blk, 0, stream>>>(hist, baseArr, cur);
  scatter2<<<ggen, blk, 0, stream>>>(A, CV, cur, baseArr);
  finalize<<<dim3(48, B_SZ), blk, 0, stream>>>(CV, BV, baseArr, sp);
  // sort pairs by j, then gather in ascending-j order
  sort_pairs<<<dim3(B_SZ), dim3(1024), 0, stream>>>(sp);
  gather_sorted<<<dim3(K_SZ / 1024, C_SZ, B_SZ), blk, 0, stream>>>(x, sp, y);
}

// Round 5
// 212.803 us; speedup vs baseline: 6.2852x; 1.8321x over previous
//
#include <hip/hip_runtime.h>
#include <stdint.h>

#define B_SZ 32
#define C_SZ 64
#define N_SZ 65536
#define K_SZ 8192
#define JCAP 80   // per j-bucket capacity (lambda=32, P(overflow) ~ 1e-7)

__device__ __forceinline__ uint32_t rotl32(uint32_t v, int r) {
  return (v << r) | (v >> (32 - r));
}

// JAX Threefry-2x32, 20 rounds.
__device__ __forceinline__ void threefry2x32(uint32_t k0, uint32_t k1,
                                             uint32_t x0, uint32_t x1,
                                             uint32_t& o0, uint32_t& o1) {
  const uint32_t ks2 = k0 ^ k1 ^ 0x1BD11BDAu;
  x0 += k0; x1 += k1;
#define TF_R(r) { x0 += x1; x1 = rotl32(x1, (r)); x1 ^= x0; }
  TF_R(13) TF_R(15) TF_R(26) TF_R(6)   x0 += k1;  x1 += ks2 + 1u;
  TF_R(17) TF_R(29) TF_R(16) TF_R(24)  x0 += ks2; x1 += k0  + 2u;
  TF_R(13) TF_R(15) TF_R(26) TF_R(6)   x0 += k0;  x1 += k1  + 3u;
  TF_R(17) TF_R(29) TF_R(16) TF_R(24)  x0 += k1;  x1 += ks2 + 4u;
  TF_R(13) TF_R(15) TF_R(26) TF_R(6)   x0 += ks2; x1 += k0  + 5u;
#undef TF_R
  o0 = x0; o1 = x1;
}

__device__ __forceinline__ void subkey_for_round(int b, int round,
                                                 uint32_t& sk0, uint32_t& sk1) {
  uint32_t c0, c1;
  threefry2x32(0u, 1u, 0u, (uint32_t)b, c0, c1);
  for (int r = 0; r < round; ++r) {
    uint32_t n0, n1;
    threefry2x32(c0, c1, 0u, 0u, n0, n1);
    c0 = n0; c1 = n1;
  }
  threefry2x32(c0, c1, 0u, 1u, sk0, sk1);
}

// zero per-batch hist (d_out tables) + per-batch j-bucket counters (d_ws)
__global__ __launch_bounds__(256) void zero_small(uint32_t* __restrict__ hist,
                                                  uint32_t* __restrict__ jcnt) {
  const int b = blockIdx.x, t = threadIdx.x;
  hist[b * 256 + t] = 0;
  jcnt[b * 256 + t] = 0;
}

// keygen + per-batch top-8-bit histogram. Packs (bits<<16)|i. 4096 elems/block.
template <int ROUND>
__global__ __launch_bounds__(256) void gen_hist(uint64_t* __restrict__ A,
                                                uint32_t* __restrict__ hist) {
  __shared__ uint32_t h[256];
  const int t = threadIdx.x, blk = blockIdx.x, b = blockIdx.y;
  h[t] = 0; __syncthreads();
  uint32_t sk0, sk1;
  subkey_for_round(b, ROUND, sk0, sk1);
  uint64_t* __restrict__ dst = A + (size_t)b * N_SZ;
  const int base = blk * 4096;
#pragma unroll
  for (int e = 0; e < 16; ++e) {
    const int i = base + e * 256 + t;
    uint32_t o0, o1;
    threefry2x32(sk0, sk1, 0u, (uint32_t)i, o0, o1);
    const uint32_t bits = o0 ^ o1;
    dst[i] = ((uint64_t)bits << 16) | (uint64_t)i;
    atomicAdd(&h[bits >> 24], 1u);
  }
  __syncthreads();
  if (h[t]) atomicAdd(&hist[b * 256 + t], h[t]);
}

// per-batch exclusive scan of 256 bucket counts -> baseArr (257) + cursors.
__global__ __launch_bounds__(256) void prefix_kernel(uint32_t* __restrict__ hist,
                                                     uint32_t* __restrict__ baseArr,
                                                     uint32_t* __restrict__ cur) {
  __shared__ uint32_t sc[256];
  const int b = blockIdx.x, d = threadIdx.x;
  const uint32_t h = hist[b * 256 + d];
  hist[b * 256 + d] = 0;
  sc[d] = h;
  __syncthreads();
  for (int off = 1; off < 256; off <<= 1) {
    const uint32_t y = (d >= off) ? sc[d - off] : 0u;
    __syncthreads();
    sc[d] += y;
    __syncthreads();
  }
  const uint32_t excl = sc[d] - h;
  baseArr[b * 257 + d] = excl;
  cur[b * 256 + d] = excl;
  if (d == 255) baseArr[b * 257 + 256] = sc[255];
}

// bucket scatter (order within bucket irrelevant: counting-rank restores it).
__global__ __launch_bounds__(256) void scatter1(const uint64_t* __restrict__ A,
                                                uint64_t* __restrict__ BV,
                                                uint32_t* __restrict__ cur) {
  __shared__ uint32_t lcnt[256];
  __shared__ uint32_t gb[256];
  const int t = threadIdx.x, blk = blockIdx.x, b = blockIdx.y;
  lcnt[t] = 0; __syncthreads();
  const uint64_t* __restrict__ src = A + (size_t)b * N_SZ + blk * 4096;
  uint64_t v[16]; uint32_t r[16], dg[16];
#pragma unroll
  for (int e = 0; e < 16; ++e) {
    v[e] = src[e * 256 + t];
    dg[e] = (uint32_t)(v[e] >> 40) & 0xFFu;
    r[e] = atomicAdd(&lcnt[dg[e]], 1u);
  }
  __syncthreads();
  if (lcnt[t]) gb[t] = atomicAdd(&cur[b * 256 + t], lcnt[t]);
  __syncthreads();
  uint64_t* __restrict__ dst = BV + (size_t)b * N_SZ;
#pragma unroll
  for (int e = 0; e < 16; ++e)
    dst[gb[dg[e]] + r[e]] = v[e];
}

__global__ __launch_bounds__(256) void scatter2(const uint64_t* __restrict__ A,
                                                uint64_t* __restrict__ CV,
                                                uint32_t* __restrict__ cur,
                                                const uint32_t* __restrict__ baseArr) {
  __shared__ uint32_t lcnt[256];
  __shared__ uint32_t gb[256];
  __shared__ uint32_t keep[256];
  const int t = threadIdx.x, blk = blockIdx.x, b = blockIdx.y;
  lcnt[t] = 0;
  keep[t] = (baseArr[b * 257 + t] < K_SZ) ? 1u : 0u;
  __syncthreads();
  const uint64_t* __restrict__ src = A + (size_t)b * N_SZ + blk * 4096;
  uint64_t v[16]; uint32_t r[16], dg[16];
#pragma unroll
  for (int e = 0; e < 16; ++e) {
    v[e] = src[e * 256 + t];
    dg[e] = (uint32_t)(v[e] >> 40) & 0xFFu;
    r[e] = keep[dg[e]] ? atomicAdd(&lcnt[dg[e]], 1u) : 0u;
  }
  __syncthreads();
  if (lcnt[t]) gb[t] = atomicAdd(&cur[b * 256 + t], lcnt[t]);
  __syncthreads();
  uint64_t* __restrict__ dst = CV + (size_t)b * N_SZ;
#pragma unroll
  for (int e = 0; e < 16; ++e)
    if (keep[dg[e]]) dst[gb[dg[e]] + r[e]] = v[e];
}

// -------- two-level counting-rank of one top-8 bucket (n <= 512) --------
// order = (key bits 23..16, key bits 15..0, pos) == stable sort by full key.
// Round 1: writes u16 value table S1v[rank] = pos.
__global__ __launch_bounds__(256) void rank_sort1(const uint64_t* __restrict__ BV,
                                                  const uint32_t* __restrict__ baseArr,
                                                  uint16_t* __restrict__ S1v) {
  __shared__ uint32_t sub[512];
  __shared__ uint16_t dg[512];
  __shared__ uint16_t idxt[512];
  __shared__ uint32_t hist[256];
  __shared__ uint32_t sc[256];
  __shared__ uint32_t cur[256];
  __shared__ uint32_t base2[257];
  const int t = threadIdx.x, u = blockIdx.x, b = blockIdx.y;
  const uint32_t base = baseArr[b * 257 + u];
  uint32_t n = baseArr[b * 257 + u + 1] - base;
  if (n > 512u) n = 512u;
  const uint64_t* __restrict__ g = BV + (size_t)b * N_SZ + base;

  hist[t] = 0; __syncthreads();
  uint64_t rec[2];
#pragma unroll
  for (int w = 0; w < 2; ++w) {
    const int e = t + w * 256;
    if (e < (int)n) {
      rec[w] = g[e];
      const uint32_t key = (uint32_t)(rec[w] >> 16);
      const uint32_t d = (key >> 16) & 0xFFu;
      sub[e] = ((key & 0xFFFFu) << 16) | (uint32_t)(rec[w] & 0xFFFFull);
      dg[e] = (uint16_t)d;
      atomicAdd(&hist[d], 1u);
    }
  }
  __syncthreads();
  sc[t] = hist[t]; __syncthreads();
  for (int off = 1; off < 256; off <<= 1) {
    const uint32_t y = (t >= off) ? sc[t - off] : 0u;
    __syncthreads();
    sc[t] += y;
    __syncthreads();
  }
  base2[t] = sc[t] - hist[t];
  cur[t] = sc[t] - hist[t];
  if (t == 255) base2[256] = sc[255];
  __syncthreads();
#pragma unroll
  for (int w = 0; w < 2; ++w) {
    const int e = t + w * 256;
    if (e < (int)n) idxt[atomicAdd(&cur[dg[e]], 1u)] = (uint16_t)e;
  }
  __syncthreads();
  uint16_t* __restrict__ out = S1v + (size_t)b * N_SZ + base;
#pragma unroll
  for (int w = 0; w < 2; ++w) {
    const int e = t + w * 256;
    if (e < (int)n) {
      const uint32_t d = dg[e], s = sub[e];
      const uint32_t lo = base2[d], hi = base2[d + 1];
      uint32_t r = 0;
      for (uint32_t i = lo; i < hi; ++i) r += (sub[idxt[i]] < s) ? 1u : 0u;
      out[d == 0 ? r : (lo + r)] = (uint16_t)(rec[w] & 0xFFFFull);
    }
  }
}

// Round 2 head buckets: same rank; emit (j,q) pair into j-bucket (j>>8).
__global__ __launch_bounds__(256) void finalize_rank(const uint64_t* __restrict__ CV,
                                                     const uint32_t* __restrict__ baseArr,
                                                     const uint16_t* __restrict__ S1v,
                                                     uint32_t* __restrict__ jcnt,
                                                     uint32_t* __restrict__ jb) {
  __shared__ uint32_t sub[512];
  __shared__ uint16_t dg[512];
  __shared__ uint16_t idxt[512];
  __shared__ uint32_t hist[256];
  __shared__ uint32_t sc[256];
  __shared__ uint32_t cur[256];
  __shared__ uint32_t base2[257];
  const int t = threadIdx.x, u = blockIdx.x, b = blockIdx.y;
  const uint32_t base = baseArr[b * 257 + u];
  if (base >= K_SZ) return;
  uint32_t n = baseArr[b * 257 + u + 1] - base;
  if (n > 512u) n = 512u;
  const uint64_t* __restrict__ g = CV + (size_t)b * N_SZ + base;

  hist[t] = 0; __syncthreads();
  uint64_t rec[2];
#pragma unroll
  for (int w = 0; w < 2; ++w) {
    const int e = t + w * 256;
    if (e < (int)n) {
      rec[w] = g[e];
      const uint32_t key = (uint32_t)(rec[w] >> 16);
      const uint32_t d = (key >> 16) & 0xFFu;
      sub[e] = ((key & 0xFFFFu) << 16) | (uint32_t)(rec[w] & 0xFFFFull);
      dg[e] = (uint16_t)d;
      atomicAdd(&hist[d], 1u);
    }
  }
  __syncthreads();
  sc[t] = hist[t]; __syncthreads();
  for (int off = 1; off < 256; off <<= 1) {
    const uint32_t y = (t >= off) ? sc[t - off] : 0u;
    __syncthreads();
    sc[t] += y;
    __syncthreads();
  }
  base2[t] = sc[t] - hist[t];
  cur[t] = sc[t] - hist[t];
  if (t == 255) base2[256] = sc[255];
  __syncthreads();
#pragma unroll
  for (int w = 0; w < 2; ++w) {
    const int e = t + w * 256;
    if (e < (int)n) idxt[atomicAdd(&cur[dg[e]], 1u)] = (uint16_t)e;
  }
  __syncthreads();
  const uint16_t* __restrict__ s1 = S1v + (size_t)b * N_SZ;
#pragma unroll
  for (int w = 0; w < 2; ++w) {
    const int e = t + w * 256;
    if (e < (int)n) {
      const uint32_t d = dg[e], s = sub[e];
      const uint32_t lo = base2[d], hi = base2[d + 1];
      uint32_t r = 0;
      for (uint32_t i = lo; i < hi; ++i) r += (sub[idxt[i]] < s) ? 1u : 0u;
      const uint32_t q = base + lo + r;
      if (q < K_SZ) {
        const uint32_t p = (uint32_t)(rec[w] & 0xFFFFull);   // round-1 rank
        const uint32_t j = (uint32_t)s1[p];                  // permutation value
        const uint32_t slot = atomicAdd(&jcnt[b * 256 + (j >> 8)], 1u);
        if (slot < JCAP)
          jb[((size_t)b * 256 + (j >> 8)) * JCAP + slot] = (j << 16) | q;
      }
    }
  }
}

// compact capped j-buckets into a dense bucket-ordered pair list sp[b][0..K).
__global__ __launch_bounds__(256) void compact_pairs(const uint32_t* __restrict__ jcnt,
                                                     const uint32_t* __restrict__ jb,
                                                     uint32_t* __restrict__ sp) {
  __shared__ uint32_t sc[256];
  __shared__ uint32_t cnt[256];
  const int b = blockIdx.x, t = threadIdx.x;
  uint32_t c = jcnt[b * 256 + t];
  if (c > JCAP) c = JCAP;
  cnt[t] = c; sc[t] = c;
  __syncthreads();
  for (int off = 1; off < 256; off <<= 1) {
    const uint32_t y = (t >= off) ? sc[t - off] : 0u;
    __syncthreads();
    sc[t] += y;
    __syncthreads();
  }
  const uint32_t base = sc[t] - cnt[t];
  const uint32_t* __restrict__ src = jb + ((size_t)b * 256 + t) * JCAP;
  uint32_t* __restrict__ dst = sp + (size_t)b * K_SZ + base;
  for (uint32_t i = 0; i < cnt[t]; ++i) dst[i] = src[i];
}

// gather: one (b,c) row per block. Random LDS writes, coalesced float4 stores.
__global__ __launch_bounds__(256) void gather_staged(const float* __restrict__ x,
                                                     const uint32_t* __restrict__ sp,
                                                     float* __restrict__ y) {
  __shared__ float row[K_SZ];   // 32 KiB
  const int t = threadIdx.x, c = blockIdx.x, b = blockIdx.y;
  const uint32_t* __restrict__ spb = sp + (size_t)b * K_SZ;
  const float* __restrict__ xr = x + ((size_t)b * C_SZ + c) * N_SZ;
#pragma unroll 8
  for (int w = 0; w < 32; ++w) {
    const uint32_t p = spb[w * 256 + t];
    row[p & 0xFFFFu] = xr[p >> 16];
  }
  __syncthreads();
  float4* __restrict__ yr4 = (float4*)(y + ((size_t)b * C_SZ + c) * K_SZ);
  const float4* __restrict__ r4 = (const float4*)row;
#pragma unroll
  for (int w = 0; w < 8; ++w) yr4[w * 256 + t] = r4[w * 256 + t];
}

extern "C" void kernel_launch(void* const* d_in, const int* in_sizes, int n_in,
                              void* d_out, int out_size, void* d_ws, size_t ws_size,
                              hipStream_t stream) {
  (void)in_sizes; (void)n_in; (void)out_size; (void)ws_size;
  const float* x = (const float*)d_in[0];
  float* y = (float*)d_out;

  // d_out (64 MiB) scratch; gather fully overwrites it and reads only x+d_ws.
  char* base = (char*)d_out;
  uint64_t* A  = (uint64_t*)base;                       // 16 MiB packed recs
  uint64_t* BV = (uint64_t*)(base + (16u << 20));       // 16 MiB round-1 bucketed
  uint64_t* CV = (uint64_t*)(base + (32u << 20));       // 16 MiB round-2 head bucketed
  uint32_t* hist    = (uint32_t*)(base + (48u << 20));             // 32 KiB
  uint32_t* baseArr = (uint32_t*)(base + (48u << 20) + (64u << 10)); // ~33 KiB
  uint32_t* cur     = (uint32_t*)(base + (48u << 20) + (128u << 10));// 32 KiB
  uint16_t* S1v     = (uint16_t*)(base + (52u << 20));             // 4 MiB u16 values
  // d_ws
  uint32_t* jcnt = (uint32_t*)d_ws;                               // 32 KiB
  uint32_t* jb   = (uint32_t*)((char*)d_ws + (64u << 10));        // 2.6 MiB
  uint32_t* sp   = (uint32_t*)((char*)d_ws + (4u << 20));         // 1 MiB

  const dim3 blk(256);
  const dim3 ggen(16, B_SZ);

  zero_small<<<dim3(B_SZ), blk, 0, stream>>>(hist, jcnt);
  // round 1
  gen_hist<0><<<ggen, blk, 0, stream>>>(A, hist);
  prefix_kernel<<<dim3(B_SZ), blk, 0, stream>>>(hist, baseArr, cur);
  scatter1<<<ggen, blk, 0, stream>>>(A, BV, cur);
  rank_sort1<<<dim3(256, B_SZ), blk, 0, stream>>>(BV, baseArr, S1v);
  // round 2
  gen_hist<1><<<ggen, blk, 0, stream>>>(A, hist);
  prefix_kernel<<<dim3(B_SZ), blk, 0, stream>>>(hist, baseArr, cur);
  scatter2<<<ggen, blk, 0, stream>>>(A, CV, cur, baseArr);
  finalize_rank<<<dim3(48, B_SZ), blk, 0, stream>>>(CV, baseArr, S1v, jcnt, jb);
  compact_pairs<<<dim3(B_SZ), blk, 0, stream>>>(jcnt, jb, sp);
  // gather
  gather_staged<<<dim3(C_SZ, B_SZ), blk, 0, stream>>>(x, sp, y);
}